// Round 14
// baseline (320.909 us; speedup 1.0000x reference)
//
#include <hip/hip_runtime.h>

#define IN_DIM 4096
#define OUT_DIM 4096
#define M_DIM 8192
#define RANK 32
#define BK 64
#define NT (IN_DIM / BK)   // 64 K-tiles

typedef __bf16 bf16x8 __attribute__((ext_vector_type(8)));
typedef float f32x4 __attribute__((ext_vector_type(4)));
typedef unsigned short u16x8 __attribute__((ext_vector_type(8)));

__device__ __forceinline__ unsigned short f2bf(float f) {
  unsigned u = __builtin_bit_cast(unsigned, f);
  u += 0x7FFF + ((u >> 16) & 1);   // round-to-nearest-even
  return (unsigned short)(u >> 16);
}

// ---------------- prep: Wb = bf16(W + A @ B^T), rank-32 via one MFMA/fragment ----------------
// (x-cast eliminated: gemm consumes x f32 directly and converts during staging)
__global__ __launch_bounds__(256) void prep_kernel(
    const float* __restrict__ W, const float* __restrict__ A,
    const float* __restrict__ B, unsigned short* __restrict__ Wb) {
  const int tid = threadIdx.x;
  __shared__ unsigned short sA[128][40];
  __shared__ unsigned short sB[128][40];
  const int lane = tid & 63;
  const int wid  = tid >> 6;
  const int wr   = wid >> 1, wc = wid & 1;
  const int li   = lane & 15, kg = lane >> 4;
  const int bRow = (blockIdx.x >> 5) * 128;   // out dim
  const int bCol = (blockIdx.x & 31) * 128;   // in dim

  for (int i = tid; i < 128 * 8; i += 256) {
    const int r = i >> 3, q = i & 7;
    const float4 va = reinterpret_cast<const float4*>(A + (size_t)(bRow + r) * RANK)[q];
    ushort4 oa;
    oa.x = f2bf(va.x); oa.y = f2bf(va.y); oa.z = f2bf(va.z); oa.w = f2bf(va.w);
    *reinterpret_cast<ushort4*>(&sA[r][q * 4]) = oa;
    const float4 vb = reinterpret_cast<const float4*>(B + (size_t)(bCol + r) * RANK)[q];
    ushort4 ob;
    ob.x = f2bf(vb.x); ob.y = f2bf(vb.y); ob.z = f2bf(vb.z); ob.w = f2bf(vb.w);
    *reinterpret_cast<ushort4*>(&sB[r][q * 4]) = ob;
  }
  __syncthreads();

  bf16x8 af[4], bq[4];
#pragma unroll
  for (int m = 0; m < 4; ++m)
    af[m] = *reinterpret_cast<const bf16x8*>(&sA[wr * 64 + m * 16 + li][kg * 8]);
#pragma unroll
  for (int n = 0; n < 4; ++n)
    bq[n] = *reinterpret_cast<const bf16x8*>(&sB[wc * 64 + n * 16 + li][kg * 8]);

  f32x4 acc[4][4];
#pragma unroll
  for (int m = 0; m < 4; ++m)
#pragma unroll
    for (int n = 0; n < 4; ++n) {
      acc[m][n] = f32x4{0.f, 0.f, 0.f, 0.f};
      acc[m][n] = __builtin_amdgcn_mfma_f32_16x16x32_bf16(af[m], bq[n], acc[m][n], 0, 0, 0);
    }

#pragma unroll
  for (int m = 0; m < 4; ++m) {
#pragma unroll
    for (int n = 0; n < 4; ++n) {
      const int col = bCol + wc * 64 + n * 16 + li;
#pragma unroll
      for (int j = 0; j < 4; ++j) {
        const int row = bRow + wr * 64 + m * 16 + kg * 4 + j;
        const size_t idx = (size_t)row * IN_DIM + col;
        Wb[idx] = f2bf(W[idx] + acc[m][n][j]);
      }
    }
  }
}

// ---------------- main GEMM: 256x256, BK=64, R6 schedule, A reg-staged from f32 x ----------------
// R6 (campaign-best) schedule; A-staging changed from gload_lds(Xb bf16) to
// {global f32 loads -> regs -> cvt -> ds_write_b128}, eliminating the x-cast
// prep (~30 us HBM). LDS byte layout/swizzle identical -> read path untouched.
// Pipelines: A1(t+1): LOAD t.ph0 -> WRITE t.ph3 -> READ (t+1).ph2
//            A0(t+1): LOAD (t-1).ph2 -> WRITE t.ph2 -> READ (t+1).ph0
// RAW: each ds_write precedes (program order) an lgkm-waited read in the same
// region; per-wave in-order lgkm completion => write done before the writer
// passes the next barrier; consumers read >=1 barrier later (audited/region).
// WAR: writes land 4-6 barriers after the target region's last reads retired.
// vmcnt: A-writes get compiler auto-waits at register use (positional counter
// also retires older B gloads). Manual vmcnt(6) at ph3 = ops issued after
// t.ph0 (A0(t+2) 4 + B0(t+2) 2) -> publishes B halves of t+1 before its BAR.
// sched_barrier(0) pins phase-granular VMEM issue order (counts stay valid).
__global__ __launch_bounds__(512, 2) void gemm_kernel(
    const float* __restrict__ Xf, const unsigned short* __restrict__ Wb,
    const float* __restrict__ bias, float* __restrict__ Y) {
  __shared__ unsigned short lds[8][8192];   // 128 KiB
  const int tid  = threadIdx.x;
  const int lane = tid & 63;
  const int wid  = tid >> 6;          // 0..7
  const int wr   = wid >> 2;          // 0..1
  const int wc   = wid & 3;           // 0..3
  const int li   = lane & 15, kg = lane >> 4;

  // XCD-aware bijective swizzle: 512 blocks = 8 XCDs x 64
  const int bid = blockIdx.x;
  const int swz = (bid & 7) * 64 + (bid >> 3);
  const int bx  = swz & 15;           // N tiles: 4096/256 = 16
  const int by  = swz >> 4;           // M tiles: 8192/256 = 32
  const int bRow = by * 256, bCol = bx * 256;

  // staging: physical chunk p = l*512 + tid; local row r = p>>3; kc = (p&7)^(r&7)
  const int kcS = (tid & 7) ^ ((tid >> 3) & 7);
  const float* srcAf[2][2];
  const unsigned short* srcB[2][2];
#pragma unroll
  for (int h = 0; h < 2; ++h)
#pragma unroll
    for (int l = 0; l < 2; ++l) {
      const int gA = l * 128 + h * 64 + (tid >> 3);
      const int gB = (l * 2 + (tid >> 8)) * 64 + h * 32 + ((tid >> 3) & 31);
      srcAf[h][l] = Xf + (size_t)(bRow + gA) * IN_DIM + kcS * 8;
      srcB[h][l]  = Wb + (size_t)(bCol + gB) * IN_DIM + kcS * 8;
    }
  char* const ldsRaw = (char*)&lds[0][0];

#define GLD(src, dstoff)                                                       \
  __builtin_amdgcn_global_load_lds(                                            \
      (const __attribute__((address_space(1))) unsigned int*)(src),            \
      (__attribute__((address_space(3))) unsigned int*)(ldsRaw + (dstoff)),    \
      16, 0, 0)
#define STAGE_B(s, h)                                                          \
  do {                                                                         \
    const int q_ = (((s) & 1) << 2) + 2 + (h);                                 \
    GLD(srcB[h][0] + (s) * BK, q_ * 16384 + tid * 16);                         \
    GLD(srcB[h][1] + (s) * BK, q_ * 16384 + 8192 + tid * 16);                  \
  } while (0)
// A staging: 4x float4 loads (8 f32 per 16B-dest sub-load), cvt, 2x b128 write
#define A_LOAD(vv, s, h)                                                       \
  do {                                                                         \
    vv[0] = *reinterpret_cast<const float4*>(srcAf[h][0] + (s) * BK);          \
    vv[1] = *reinterpret_cast<const float4*>(srcAf[h][0] + (s) * BK + 4);      \
    vv[2] = *reinterpret_cast<const float4*>(srcAf[h][1] + (s) * BK);          \
    vv[3] = *reinterpret_cast<const float4*>(srcAf[h][1] + (s) * BK + 4);      \
  } while (0)
#define A_WRITE(vv, s, h)                                                      \
  do {                                                                         \
    const int q_ = (((s) & 1) << 2) + (h);                                     \
    u16x8 o0_, o1_;                                                            \
    o0_[0] = f2bf(vv[0].x); o0_[1] = f2bf(vv[0].y);                            \
    o0_[2] = f2bf(vv[0].z); o0_[3] = f2bf(vv[0].w);                            \
    o0_[4] = f2bf(vv[1].x); o0_[5] = f2bf(vv[1].y);                            \
    o0_[6] = f2bf(vv[1].z); o0_[7] = f2bf(vv[1].w);                            \
    o1_[0] = f2bf(vv[2].x); o1_[1] = f2bf(vv[2].y);                            \
    o1_[2] = f2bf(vv[2].z); o1_[3] = f2bf(vv[2].w);                            \
    o1_[4] = f2bf(vv[3].x); o1_[5] = f2bf(vv[3].y);                            \
    o1_[6] = f2bf(vv[3].z); o1_[7] = f2bf(vv[3].w);                            \
    *reinterpret_cast<u16x8*>(ldsRaw + q_ * 16384 + tid * 16) = o0_;           \
    *reinterpret_cast<u16x8*>(ldsRaw + q_ * 16384 + 8192 + tid * 16) = o1_;    \
  } while (0)
#define BAR() __builtin_amdgcn_s_barrier()
#define SB()  __builtin_amdgcn_sched_barrier(0)

  // fragment read addressing (proven conflict-free, unchanged)
  const int rowAoff = (wr * 64 + li) * 64;
  const int rowBoff = (wc * 32 + li) * 64;
  int kx[2];
  kx[0] = ((0 * 4 + kg) ^ (li & 7)) * 8;
  kx[1] = ((1 * 4 + kg) ^ (li & 7)) * 8;

  bf16x8 af[4][2], bq[4][2];
  float4 a0v[4], a1v[4];
  f32x4 acc[8][4];
#pragma unroll
  for (int m = 0; m < 8; ++m)
#pragma unroll
    for (int n = 0; n < 4; ++n) acc[m][n] = f32x4{0.f, 0.f, 0.f, 0.f};

#define RD_A(ms_)                                                              \
  do {                                                                         \
    const unsigned short* b_ = &lds[(dcur << 2) + (ms_)][0] + rowAoff;         \
    _Pragma("unroll") for (int mq = 0; mq < 4; ++mq)                           \
      _Pragma("unroll") for (int ks = 0; ks < 2; ++ks)                         \
        af[mq][ks] =                                                           \
            *reinterpret_cast<const bf16x8*>(b_ + mq * 1024 + kx[ks]);         \
  } while (0)
#define RD_B(ns_)                                                              \
  do {                                                                         \
    const unsigned short* b_ = &lds[(dcur << 2) + 2 + (ns_)][0] + rowBoff;     \
    _Pragma("unroll") for (int nq = 0; nq < 2; ++nq)                           \
      _Pragma("unroll") for (int ks = 0; ks < 2; ++ks)                         \
        bq[(ns_) * 2 + nq][ks] =                                               \
            *reinterpret_cast<const bf16x8*>(b_ + nq * 1024 + kx[ks]);         \
  } while (0)
#define MM(ms_, ns_)                                                           \
  do {                                                                         \
    __builtin_amdgcn_s_setprio(1);                                             \
    _Pragma("unroll") for (int mq = 0; mq < 4; ++mq)                           \
      _Pragma("unroll") for (int nq = 0; nq < 2; ++nq)                         \
        _Pragma("unroll") for (int ks = 0; ks < 2; ++ks)                       \
          acc[(ms_) * 4 + mq][(ns_) * 2 + nq] =                                \
              __builtin_amdgcn_mfma_f32_16x16x32_bf16(                         \
                  af[mq][ks], bq[(ns_) * 2 + nq][ks],                          \
                  acc[(ms_) * 4 + mq][(ns_) * 2 + nq], 0, 0, 0);               \
    __builtin_amdgcn_s_setprio(0);                                             \
  } while (0)

  // ---- prologue: tile 0 A via regs, B via gload; prefetch A0(1), B0(1) ----
  A_LOAD(a0v, 0, 0);                    // 4 loads
  A_LOAD(a1v, 0, 1);                    // 4 loads
  STAGE_B(0, 0); STAGE_B(0, 1);         // 4 gloads
  SB();
  A_WRITE(a0v, 0, 0);                   // auto-vmcnt(8); writes region A(0,0)
  A_WRITE(a1v, 0, 1);                   // auto-vmcnt(4); region A(0,1)
  SB();
  A_LOAD(a0v, 1, 0);                    // 4 loads (tile 1 A0)
  STAGE_B(1, 0);                        // 2 gloads
  asm volatile("s_waitcnt vmcnt(6)" ::: "memory");   // B(0) halves published
  BAR();

  for (int t = 0; t < NT; ++t) {
    const int dcur = t & 1;
    const bool st1 = (t + 1 < NT), st2 = (t + 2 < NT);
    // ph0
    if (st1) { STAGE_B(t + 1, 1); A_LOAD(a1v, t + 1, 1); }
    RD_A(0); RD_B(0);
    BAR();
    MM(0, 0);
    // ph1
    RD_B(1);
    BAR();
    MM(0, 1);
    // ph2
    SB();
    if (st1) A_WRITE(a0v, t + 1, 0);    // region A(dn,0); auto-vmcnt
    if (st2) A_LOAD(a0v, t + 2, 0);
    RD_A(1);
    BAR();
    MM(1, 0);
    // ph3
    SB();
    if (st2) STAGE_B(t + 2, 0);
    if (st1) A_WRITE(a1v, t + 1, 1);    // region A(dn,1); auto-vmcnt
    if (st2) {
      asm volatile("s_waitcnt vmcnt(6)" ::: "memory");
    } else if (st1) {
      asm volatile("s_waitcnt vmcnt(0)" ::: "memory");
    }
    BAR();
    MM(1, 1);
  }
#undef GLD
#undef STAGE_B
#undef A_LOAD
#undef A_WRITE
#undef RD_A
#undef RD_B
#undef MM
#undef BAR
#undef SB

  // ---- epilogue: C/D layout col = li, row = kg*4 + j (m89-verified) ----
#pragma unroll
  for (int nf = 0; nf < 4; ++nf) {
    const int col = bCol + wc * 64 + nf * 16 + li;
    const float bv = bias[col];
#pragma unroll
    for (int mf = 0; mf < 8; ++mf) {
      const int row0 = bRow + wr * 128 + mf * 16 + kg * 4;
#pragma unroll
      for (int j = 0; j < 4; ++j)
        Y[(size_t)(row0 + j) * OUT_DIM + col] = acc[mf][nf][j] + bv;
    }
  }
}

extern "C" void kernel_launch(void* const* d_in, const int* in_sizes, int n_in,
                              void* d_out, int out_size, void* d_ws, size_t ws_size,
                              hipStream_t stream) {
  const float* x    = (const float*)d_in[0];
  const float* w    = (const float*)d_in[1];
  const float* bias = (const float*)d_in[2];
  const float* A    = (const float*)d_in[3];
  const float* B    = (const float*)d_in[4];
  float* y = (float*)d_out;

  const size_t wb_bytes = (size_t)OUT_DIM * IN_DIM * 2;        // 32 MiB
  if (ws_size < wb_bytes) return;

  unsigned short* Wb = (unsigned short*)d_ws;

  prep_kernel<<<1024, 256, 0, stream>>>(w, A, B, Wb);
  gemm_kernel<<<(M_DIM / 256) * (OUT_DIM / 256), 512, 0, stream>>>(x, Wb, bias, y);
}

// Round 15
// 276.904 us; speedup vs baseline: 1.1589x; 1.1589x over previous
//
#include <hip/hip_runtime.h>

#define IN_DIM 4096
#define OUT_DIM 4096
#define M_DIM 8192
#define RANK 32
#define BK 64
#define NT (IN_DIM / BK)   // 64 K-tiles

typedef __bf16 bf16x8 __attribute__((ext_vector_type(8)));
typedef float f32x4 __attribute__((ext_vector_type(4)));

__device__ __forceinline__ unsigned short f2bf(float f) {
  unsigned u = __builtin_bit_cast(unsigned, f);
  u += 0x7FFF + ((u >> 16) & 1);   // round-to-nearest-even
  return (unsigned short)(u >> 16);
}

// ---------------- fused prep: blocks [0,1024) do Wb, [1024,1536) do Xb ----------------
__global__ __launch_bounds__(256) void prep_kernel(
    const float* __restrict__ X, unsigned short* __restrict__ Xb,
    const float* __restrict__ W, const float* __restrict__ A,
    const float* __restrict__ B, unsigned short* __restrict__ Wb) {
  const int tid = threadIdx.x;
  if (blockIdx.x >= 1024) {
    // ---- X cast path ----
    const int idx0 = (blockIdx.x - 1024) * 256 + tid;
    const int stride = 512 * 256;
    const int total4 = (M_DIM * IN_DIM) / 4;
    for (int i = idx0; i < total4; i += stride) {
      const float4 v = reinterpret_cast<const float4*>(X)[i];
      ushort4 o;
      o.x = f2bf(v.x); o.y = f2bf(v.y); o.z = f2bf(v.z); o.w = f2bf(v.w);
      reinterpret_cast<ushort4*>(Xb)[i] = o;
    }
    return;
  }
  // ---- W path: Wb = bf16(W + A @ B^T), rank-32 via one MFMA per fragment ----
  __shared__ unsigned short sA[128][40];
  __shared__ unsigned short sB[128][40];
  const int lane = tid & 63;
  const int wid  = tid >> 6;
  const int wr   = wid >> 1, wc = wid & 1;
  const int li   = lane & 15, kg = lane >> 4;
  const int bRow = (blockIdx.x >> 5) * 128;   // out dim
  const int bCol = (blockIdx.x & 31) * 128;   // in dim

  for (int i = tid; i < 128 * 8; i += 256) {
    const int r = i >> 3, q = i & 7;
    const float4 va = reinterpret_cast<const float4*>(A + (size_t)(bRow + r) * RANK)[q];
    ushort4 oa;
    oa.x = f2bf(va.x); oa.y = f2bf(va.y); oa.z = f2bf(va.z); oa.w = f2bf(va.w);
    *reinterpret_cast<ushort4*>(&sA[r][q * 4]) = oa;
    const float4 vb = reinterpret_cast<const float4*>(B + (size_t)(bCol + r) * RANK)[q];
    ushort4 ob;
    ob.x = f2bf(vb.x); ob.y = f2bf(vb.y); ob.z = f2bf(vb.z); ob.w = f2bf(vb.w);
    *reinterpret_cast<ushort4*>(&sB[r][q * 4]) = ob;
  }
  __syncthreads();

  bf16x8 af[4], bq[4];
#pragma unroll
  for (int m = 0; m < 4; ++m)
    af[m] = *reinterpret_cast<const bf16x8*>(&sA[wr * 64 + m * 16 + li][kg * 8]);
#pragma unroll
  for (int n = 0; n < 4; ++n)
    bq[n] = *reinterpret_cast<const bf16x8*>(&sB[wc * 64 + n * 16 + li][kg * 8]);

  f32x4 acc[4][4];
#pragma unroll
  for (int m = 0; m < 4; ++m)
#pragma unroll
    for (int n = 0; n < 4; ++n) {
      acc[m][n] = f32x4{0.f, 0.f, 0.f, 0.f};
      acc[m][n] = __builtin_amdgcn_mfma_f32_16x16x32_bf16(af[m], bq[n], acc[m][n], 0, 0, 0);
    }

#pragma unroll
  for (int m = 0; m < 4; ++m) {
#pragma unroll
    for (int n = 0; n < 4; ++n) {
      const int col = bCol + wc * 64 + n * 16 + li;
#pragma unroll
      for (int j = 0; j < 4; ++j) {
        const int row = bRow + wr * 64 + m * 16 + kg * 4 + j;
        const size_t idx = (size_t)row * IN_DIM + col;
        Wb[idx] = f2bf(W[idx] + acc[m][n][j]);
      }
    }
  }
}

// ---------------- main GEMM: 256x256 tile, BK=64, 4-phase, ONE barrier/phase ----------------
// Campaign-best structure (R6/R13). Tested and rejected: fragment prefetch (R7),
// sched_barrier pinning (R8), MFMA-leading SGB (R9), DS-leading SGB + peeled
// branch-free loop (R10), 2-blocks/CU TLP x2 geometries (R11/R12), fused
// reg-staged x-cast (R14, -40%: in-window cvt+ds_write serializes against the
// gload_lds queue via the shared positional vmcnt). 256²/BK=64 minimizes LDS
// bytes/FLOP; plateau = partial LDS/MFMA overlap at ~1074 cyc/window.
//   ph0: [STAGE_B(t+1,1); STAGE_A(t+1,1)] RD_A(0),RD_B(0) | BAR | MM(0,0)
//   ph1:                                   RD_B(1)         | BAR | MM(0,1)
//   ph2: [STAGE_A(t+2,0)]                  RD_A(1)         | BAR | MM(1,0)
//   ph3: [STAGE_B(t+2,0)] vmcnt(4)                         | BAR | MM(1,1)
// WAR: stage-write to region R >=1 barrier after the MM that lgkm-waits R's
// last read. vmcnt: 8 issued/tile; queue at ph3 = 12; vmcnt(4) retires exactly
// tile t+1's 8 loads. Never drains to 0 in steady state.
__global__ __launch_bounds__(512, 2) void gemm_kernel(
    const unsigned short* __restrict__ Xb, const unsigned short* __restrict__ Wb,
    const float* __restrict__ bias, float* __restrict__ Y) {
  __shared__ unsigned short lds[8][8192];   // 128 KiB
  const int tid  = threadIdx.x;
  const int lane = tid & 63;
  const int wid  = tid >> 6;          // 0..7
  const int wr   = wid >> 2;          // 0..1
  const int wc   = wid & 3;           // 0..3
  const int li   = lane & 15, kg = lane >> 4;

  // XCD-aware bijective swizzle: 512 blocks = 8 XCDs x 64
  const int bid = blockIdx.x;
  const int swz = (bid & 7) * 64 + (bid >> 3);
  const int bx  = swz & 15;           // N tiles: 4096/256 = 16
  const int by  = swz >> 4;           // M tiles: 8192/256 = 32
  const int bRow = by * 256, bCol = bx * 256;

  // staging: physical chunk p = l*512 + tid; local row r = p>>3; kc = (p&7)^(r&7)
  const int kcS = (tid & 7) ^ ((tid >> 3) & 7);
  const unsigned short* srcA[2][2];
  const unsigned short* srcB[2][2];
#pragma unroll
  for (int h = 0; h < 2; ++h)
#pragma unroll
    for (int l = 0; l < 2; ++l) {
      const int gA = l * 128 + h * 64 + (tid >> 3);
      const int gB = (l * 2 + (tid >> 8)) * 64 + h * 32 + ((tid >> 3) & 31);
      srcA[h][l] = Xb + (size_t)(bRow + gA) * IN_DIM + kcS * 8;
      srcB[h][l] = Wb + (size_t)(bCol + gB) * IN_DIM + kcS * 8;
    }
  char* const ldsRaw = (char*)&lds[0][0];

#define GLD(src, dstoff)                                                       \
  __builtin_amdgcn_global_load_lds(                                            \
      (const __attribute__((address_space(1))) unsigned int*)(src),            \
      (__attribute__((address_space(3))) unsigned int*)(ldsRaw + (dstoff)),    \
      16, 0, 0)
#define STAGE_A(s, h)                                                          \
  do {                                                                         \
    const int q_ = (((s) & 1) << 2) + (h);                                     \
    GLD(srcA[h][0] + (s) * BK, q_ * 16384 + tid * 16);                         \
    GLD(srcA[h][1] + (s) * BK, q_ * 16384 + 8192 + tid * 16);                  \
  } while (0)
#define STAGE_B(s, h)                                                          \
  do {                                                                         \
    const int q_ = (((s) & 1) << 2) + 2 + (h);                                 \
    GLD(srcB[h][0] + (s) * BK, q_ * 16384 + tid * 16);                         \
    GLD(srcB[h][1] + (s) * BK, q_ * 16384 + 8192 + tid * 16);                  \
  } while (0)
#define BAR() __builtin_amdgcn_s_barrier()

  // fragment read addressing (conflict-free: bank-quad = (ks*4+kg)^(li&7)
  // covers all 8 quads per 16-lane group)
  const int rowAoff = (wr * 64 + li) * 64;
  const int rowBoff = (wc * 32 + li) * 64;
  int kx[2];
  kx[0] = ((0 * 4 + kg) ^ (li & 7)) * 8;
  kx[1] = ((1 * 4 + kg) ^ (li & 7)) * 8;

  bf16x8 af[4][2], bq[4][2];
  f32x4 acc[8][4];
#pragma unroll
  for (int m = 0; m < 8; ++m)
#pragma unroll
    for (int n = 0; n < 4; ++n) acc[m][n] = f32x4{0.f, 0.f, 0.f, 0.f};

#define RD_A(ms_)                                                              \
  do {                                                                         \
    const unsigned short* b_ = &lds[(dcur << 2) + (ms_)][0] + rowAoff;         \
    _Pragma("unroll") for (int mq = 0; mq < 4; ++mq)                           \
      _Pragma("unroll") for (int ks = 0; ks < 2; ++ks)                         \
        af[mq][ks] =                                                           \
            *reinterpret_cast<const bf16x8*>(b_ + mq * 1024 + kx[ks]);         \
  } while (0)
#define RD_B(ns_)                                                              \
  do {                                                                         \
    const unsigned short* b_ = &lds[(dcur << 2) + 2 + (ns_)][0] + rowBoff;     \
    _Pragma("unroll") for (int nq = 0; nq < 2; ++nq)                           \
      _Pragma("unroll") for (int ks = 0; ks < 2; ++ks)                         \
        bq[(ns_) * 2 + nq][ks] =                                               \
            *reinterpret_cast<const bf16x8*>(b_ + nq * 1024 + kx[ks]);         \
  } while (0)
#define MM(ms_, ns_)                                                           \
  do {                                                                         \
    __builtin_amdgcn_s_setprio(1);                                             \
    _Pragma("unroll") for (int mq = 0; mq < 4; ++mq)                           \
      _Pragma("unroll") for (int nq = 0; nq < 2; ++nq)                         \
        _Pragma("unroll") for (int ks = 0; ks < 2; ++ks)                       \
          acc[(ms_) * 4 + mq][(ns_) * 2 + nq] =                                \
              __builtin_amdgcn_mfma_f32_16x16x32_bf16(                         \
                  af[mq][ks], bq[(ns_) * 2 + nq][ks],                          \
                  acc[(ms_) * 4 + mq][(ns_) * 2 + nq], 0, 0, 0);               \
    __builtin_amdgcn_s_setprio(0);                                             \
  } while (0)

  // ---- prologue: tile 0 (8 loads) + A0,B0 of tile 1 (4 loads); drain tile 0 ----
  STAGE_A(0, 0); STAGE_B(0, 0); STAGE_A(0, 1); STAGE_B(0, 1);
  STAGE_A(1, 0); STAGE_B(1, 0);
  asm volatile("s_waitcnt vmcnt(4)" ::: "memory");
  BAR();

  for (int t = 0; t < NT; ++t) {
    const int dcur = t & 1;
    const bool st1 = (t + 1 < NT), st2 = (t + 2 < NT);
    // ph0
    if (st1) { STAGE_B(t + 1, 1); STAGE_A(t + 1, 1); }
    RD_A(0); RD_B(0);
    BAR();
    MM(0, 0);
    // ph1
    RD_B(1);
    BAR();
    MM(0, 1);
    // ph2
    if (st2) STAGE_A(t + 2, 0);
    RD_A(1);
    BAR();
    MM(1, 0);
    // ph3
    if (st2) {
      STAGE_B(t + 2, 0);
      asm volatile("s_waitcnt vmcnt(4)" ::: "memory");
    } else {
      asm volatile("s_waitcnt vmcnt(0)" ::: "memory");
    }
    BAR();
    MM(1, 1);
  }
#undef GLD
#undef STAGE_A
#undef STAGE_B
#undef RD_A
#undef RD_B
#undef MM
#undef BAR

  // ---- epilogue: C/D layout col = li, row = kg*4 + j (m89-verified) ----
#pragma unroll
  for (int nf = 0; nf < 4; ++nf) {
    const int col = bCol + wc * 64 + nf * 16 + li;
    const float bv = bias[col];
#pragma unroll
    for (int mf = 0; mf < 8; ++mf) {
      const int row0 = bRow + wr * 128 + mf * 16 + kg * 4;
#pragma unroll
      for (int j = 0; j < 4; ++j)
        Y[(size_t)(row0 + j) * OUT_DIM + col] = acc[mf][nf][j] + bv;
    }
  }
}

extern "C" void kernel_launch(void* const* d_in, const int* in_sizes, int n_in,
                              void* d_out, int out_size, void* d_ws, size_t ws_size,
                              hipStream_t stream) {
  const float* x    = (const float*)d_in[0];
  const float* w    = (const float*)d_in[1];
  const float* bias = (const float*)d_in[2];
  const float* A    = (const float*)d_in[3];
  const float* B    = (const float*)d_in[4];
  float* y = (float*)d_out;

  const size_t xb_bytes = (size_t)M_DIM * IN_DIM * 2;          // 64 MiB
  const size_t wb_bytes = (size_t)OUT_DIM * IN_DIM * 2;        // 32 MiB
  if (ws_size < xb_bytes + wb_bytes) return;

  unsigned short* Xb = (unsigned short*)d_ws;
  unsigned short* Wb = (unsigned short*)((char*)d_ws + xb_bytes);

  prep_kernel<<<1536, 256, 0, stream>>>(x, Xb, w, A, B, Wb);
  gemm_kernel<<<(M_DIM / 256) * (OUT_DIM / 256), 512, 0, stream>>>(Xb, Wb, bias, y);
}